// Round 12
// baseline (320.734 us; speedup 1.0000x reference)
//
#include <hip/hip_runtime.h>
#include <hip/hip_bf16.h>
#include <stdint.h>

typedef __attribute__((ext_vector_type(8)))  short    short8;
typedef __attribute__((ext_vector_type(4)))  float    floatx4;
typedef __attribute__((ext_vector_type(16))) float    floatx16;
typedef __attribute__((ext_vector_type(2)))  uint32_t uintx2;

// HW packed fp32->bf16 (RTNE), low half = first operand.
static __device__ __forceinline__ uint32_t cvtpk(float lo, float hi) {
  uint32_t r;
  asm("v_cvt_pk_bf16_f32 %0, %1, %2" : "=v"(r) : "v"(lo), "v"(hi));
  return r;
}

#define MFMA32(a, b, c) __builtin_amdgcn_mfma_f32_32x32x16_bf16((a), (b), (c), 0, 0, 0)

constexpr int S_LEN = 2048;
constexpr int DH    = 64;
constexpr int QBLK  = 32;    // ONE wave per block: no s_barrier anywhere
constexpr int KVBLK = 64;
constexpr int NT    = S_LEN / KVBLK;   // 32

// permlane32_swap: new_a = [a.lo32, b.lo32] ; new_b = [a.hi32, b.hi32]
static __device__ __forceinline__ void swap32(uint32_t& a, uint32_t& b, int hi) {
#if __has_builtin(__builtin_amdgcn_permlane32_swap)
  typedef int intx2 __attribute__((ext_vector_type(2)));
  intx2 r = __builtin_amdgcn_permlane32_swap((int)a, (int)b, false, false);
  a = (uint32_t)r[0]; b = (uint32_t)r[1];
#else
  uint32_t pa = (uint32_t)__shfl_xor((int)a, 32, 64);
  uint32_t pb = (uint32_t)__shfl_xor((int)b, 32, 64);
  uint32_t na = hi ? pb : a;
  uint32_t nb = hi ? b  : pa;
  a = na; b = nb;
#endif
}

// 64-thread block = 1 wave. Second arg 2 => 256-reg/wave budget (2 waves/SIMD).
__global__ __launch_bounds__(64, 2)
void attn_fwd(const float* __restrict__ Q, const float* __restrict__ V,
              const float* __restrict__ K, const float* __restrict__ AM,
              const float* __restrict__ SM, float* __restrict__ O)
{
  // SINGLE-buffered wave-private tiles. Race-free without barriers because DS
  // ops of one wave execute in program order: writes of tile t+1 are issued
  // after the reads of tile t (K after QK^T, V after PV).
  __shared__ ushort Kl[KVBLK * DH];   // [kv][d] bf16, chunk^=(row&7) swizzle (8 KB)
  __shared__ ushort Vt[DH * KVBLK];   // [d][kv] bf16, swizzled (8 KB)

  const int bh   = blockIdx.x;
  const int qt   = blockIdx.y;
  const int lane = threadIdx.x;       // 0..63
  const int l31  = lane & 31;
  const int hi   = lane >> 5;

  const float* qptr  = Q  + (size_t)bh * S_LEN * DH;
  const float* kptr  = K  + (size_t)bh * S_LEN * DH;
  const float* vptr  = V  + (size_t)bh * S_LEN * DH;
  const float* amptr = AM + (size_t)(bh >> 4) * S_LEN * S_LEN;
  const float* smptr = SM + (size_t)(bh >> 4) * S_LEN;
  float* optr = O + (size_t)bh * S_LEN * DH;

  const int qw = qt * QBLK;           // this wave's 32 q rows

  // ---- Q fragments: lane holds Q[qw + l31][s*16 + hi*8 + 0..7] ----
  short8 qf[4];
  {
    const float* p = qptr + (size_t)(qw + l31) * DH + hi * 8;
    #pragma unroll
    for (int s = 0; s < 4; ++s) {
      floatx4 f0 = *(const floatx4*)(p + s * 16);
      floatx4 f1 = *(const floatx4*)(p + s * 16 + 4);
      union { uint32_t u[4]; short8 v; } w;
      w.u[0] = cvtpk(f0[0], f0[1]); w.u[1] = cvtpk(f0[2], f0[3]);
      w.u[2] = cvtpk(f1[0], f1[1]); w.u[3] = cvtpk(f1[2], f1[3]);
      qf[s] = w.v;
    }
  }

  // staging geometry (whole wave stages the whole 64x64 tile)
  const int ksw = lane & 7;           // K: lane owns kv row `lane`
  const int vr0 = (lane & 15) * 4;    // V: lane owns 4 kv rows ...
  const int vd0 = (lane >> 4) * 16;   //    ... x 16 d columns

  floatx4 stgA[8], stgB[8];           // two 32-reg staging sets
  floatx4 amx[2][4];                  // am fragments (reloaded in place per tile)

  auto LOADK = [&](int t, int h, floatx4 (&s)[8]) {   // half h: d [h*32, h*32+32)
    const float* g = kptr + (size_t)(t * KVBLK + lane) * DH + h * 32;
    #pragma unroll
    for (int j = 0; j < 8; ++j) s[j] = ((const floatx4*)g)[j];
  };
  auto WRITEK = [&](int h, floatx4 (&s)[8]) {
    #pragma unroll
    for (int j = 0; j < 4; ++j) {
      union { uint32_t u[4]; short8 v; } w;
      w.u[0] = cvtpk(s[2 * j][0], s[2 * j][1]);
      w.u[1] = cvtpk(s[2 * j][2], s[2 * j][3]);
      w.u[2] = cvtpk(s[2 * j + 1][0], s[2 * j + 1][1]);
      w.u[3] = cvtpk(s[2 * j + 1][2], s[2 * j + 1][3]);
      *(short8*)&Kl[lane * 64 + (((h * 4 + j) ^ ksw) * 8)] = w.v;
    }
  };
  auto LOADV = [&](int t, int h, floatx4 (&s)[8]) {   // half h: d [vd0+h*8, +8)
    #pragma unroll
    for (int r = 0; r < 4; ++r) {
      const float* g = vptr + (size_t)(t * KVBLK + vr0 + r) * DH + vd0 + h * 8;
      s[r * 2]     = ((const floatx4*)g)[0];
      s[r * 2 + 1] = ((const floatx4*)g)[1];
    }
  };
  auto WRITEV = [&](int h, floatx4 (&s)[8]) {
    #pragma unroll
    for (int dd = 0; dd < 8; ++dd) {
      const int d  = vd0 + h * 8 + dd;
      const int q4 = dd >> 2, r4 = dd & 3;
      uintx2 w;
      w[0] = cvtpk(s[0 + q4][r4], s[2 + q4][r4]);   // kv rows vr0, vr0+1
      w[1] = cvtpk(s[4 + q4][r4], s[6 + q4][r4]);   // kv rows vr0+2, vr0+3
      const int ch = (vr0 >> 3) ^ (d & 7);
      *(uintx2*)&Vt[d * 64 + ch * 8 + (vr0 & 7)] = w;
    }
  };
  auto LOADAM = [&](int t) {
    const float* base = amptr + (size_t)(qw + l31) * S_LEN + t * KVBLK + hi * 4;
    #pragma unroll
    for (int blk = 0; blk < 2; ++blk)
      #pragma unroll
      for (int j = 0; j < 4; ++j)
        amx[blk][j] = *(const floatx4*)(base + blk * 32 + j * 8);
  };

  // ---- prologue: stage tile 0 (no barrier needed — single wave) ----
  LOADK(0, 0, stgA); LOADK(0, 1, stgB);
  WRITEK(0, stgA);   WRITEK(1, stgB);
  LOADV(0, 0, stgA); LOADV(0, 1, stgB);
  WRITEV(0, stgA);   WRITEV(1, stgB);
  LOADAM(0);

  float m_run = -3.0e38f, l_run = 0.f;
  floatx16 oacc[2];
  #pragma unroll
  for (int db = 0; db < 2; ++db)
    #pragma unroll
    for (int r = 0; r < 16; ++r) oacc[db][r] = 0.f;

  #pragma unroll 1
  for (int t = 0; t < NT; ++t) {
    const int tn = (t + 1 < NT) ? t + 1 : NT - 1;

    // ---- QK^T: sc[blk] = S^T[kv][q]; lane q=l31, kv = blk*32+crow(r,hi) ----
    floatx16 sc[2];
    __builtin_amdgcn_s_setprio(1);
    #pragma unroll
    for (int blk = 0; blk < 2; ++blk) {
      #pragma unroll
      for (int r = 0; r < 16; ++r) sc[blk][r] = 0.f;
      const int row = blk * 32 + l31;
      const int sw  = row & 7;
      #pragma unroll
      for (int s = 0; s < 4; ++s) {
        short8 kf = *(const short8*)&Kl[row * 64 + ((s * 2 + hi) ^ sw) * 8];
        sc[blk] = MFMA32(kf, qf[s], sc[blk]);
      }
    }
    __builtin_amdgcn_s_setprio(0);

    // issue next-tile K half 0 (written below, under softmax cover)
    LOADK(tn, 0, stgA);

    // ---- scores in place (consumes amx of tile t) ----
    float pmax = -3.0e38f;
    #pragma unroll
    for (int blk = 0; blk < 2; ++blk)
      #pragma unroll
      for (int r = 0; r < 16; ++r) {
        const float v = fmaf(sc[blk][r], 0.125f, amx[blk][r >> 2][r & 3]);
        sc[blk][r] = v;
        pmax = fmaxf(pmax, v);
      }
    pmax = fmaxf(pmax, __shfl_xor(pmax, 32, 64));

    // amx dead: reload for next tile; issue K half 1
    LOADAM(tn);
    LOADK(tn, 1, stgB);

    // ---- online rescale (skip is bit-exact when no row grew: fac==1.0) ----
    if (__any(pmax > m_run)) {
      const float mnew = fmaxf(m_run, pmax);
      const float fac  = __expf(m_run - mnew);
      float fw[16];
      #pragma unroll
      for (int r = 0; r < 16; ++r)
        fw[r] = __shfl(fac, (r & 3) + 8 * (r >> 2) + 4 * hi, 64);
      #pragma unroll
      for (int db = 0; db < 2; ++db)
        #pragma unroll
        for (int r = 0; r < 16; ++r) oacc[db][r] *= fw[r];
      l_run *= fac;
      m_run = mnew;
    }

    // K half 0 -> LDS (safe: this tile's K reads already issued; DS in-order)
    WRITEK(0, stgA);

    // ---- P = exp(s - m) in place; denominator from UNROUNDED fp32 P ----
    float ssum = 0.f;
    #pragma unroll
    for (int blk = 0; blk < 2; ++blk)
      #pragma unroll
      for (int r = 0; r < 16; ++r) {
        const float e = __expf(sc[blk][r] - m_run);
        sc[blk][r] = e;
        ssum += e;
      }
    ssum += __shfl_xor(ssum, 32, 64);
    l_run += ssum;

    // K half 1 -> LDS; issue next-tile V halves (written only AFTER PV)
    WRITEK(1, stgB);
    LOADV(tn, 0, stgA);

    // ---- seq_mask fragments (global broadcast, L2-hot) ----
    floatx4 smv[2][4];
    #pragma unroll
    for (int blk = 0; blk < 2; ++blk)
      #pragma unroll
      for (int j = 0; j < 4; ++j)
        smv[blk][j] = *(const floatx4*)(smptr + t * KVBLK + blk * 32 + hi * 4 + j * 8);

    LOADV(tn, 1, stgB);

    // ---- (P * sm) -> bf16 A-fragments (cvt_pk + permlane32_swap) ----
    uint32_t pw[2][2][4];
    #pragma unroll
    for (int blk = 0; blk < 2; ++blk)
      #pragma unroll
      for (int ks = 0; ks < 2; ++ks) {
        uint32_t w0 = cvtpk(sc[blk][ks * 8 + 0] * smv[blk][ks * 2 + 0][0],
                            sc[blk][ks * 8 + 1] * smv[blk][ks * 2 + 0][1]);
        uint32_t w1 = cvtpk(sc[blk][ks * 8 + 2] * smv[blk][ks * 2 + 0][2],
                            sc[blk][ks * 8 + 3] * smv[blk][ks * 2 + 0][3]);
        uint32_t w2 = cvtpk(sc[blk][ks * 8 + 4] * smv[blk][ks * 2 + 1][0],
                            sc[blk][ks * 8 + 5] * smv[blk][ks * 2 + 1][1]);
        uint32_t w3 = cvtpk(sc[blk][ks * 8 + 6] * smv[blk][ks * 2 + 1][2],
                            sc[blk][ks * 8 + 7] * smv[blk][ks * 2 + 1][3]);
        swap32(w0, w2, hi);
        swap32(w1, w3, hi);
        pw[blk][ks][0] = w0; pw[blk][ks][1] = w1;
        pw[blk][ks][2] = w2; pw[blk][ks][3] = w3;
      }

    // ---- PV: oacc[db] += (P.sm)(32q x 64kv) . V(64kv x 64d) ----
    __builtin_amdgcn_s_setprio(1);
    #pragma unroll
    for (int blk = 0; blk < 2; ++blk)
      #pragma unroll
      for (int ks = 0; ks < 2; ++ks) {
        union { uint32_t u[4]; short8 s; } af;
        af.u[0] = pw[blk][ks][0]; af.u[1] = pw[blk][ks][1];
        af.u[2] = pw[blk][ks][2]; af.u[3] = pw[blk][ks][3];
        #pragma unroll
        for (int db = 0; db < 2; ++db) {
          const int row = db * 32 + l31;
          const int ch  = (blk * 4 + ks * 2 + hi) ^ (row & 7);
          short8 vf = *(const short8*)&Vt[row * 64 + ch * 8];
          oacc[db] = MFMA32(af.s, vf, oacc[db]);
        }
      }
    __builtin_amdgcn_s_setprio(0);

    // V halves -> LDS (after PV's V reads; loads issued ~500 cyc ago)
    WRITEV(0, stgA);
    WRITEV(1, stgB);
  }

  // ---- epilogue: out = oacc / l ----
  const float inv = 1.0f / l_run;
  float iw[16];
  #pragma unroll
  for (int r = 0; r < 16; ++r)
    iw[r] = __shfl(inv, (r & 3) + 8 * (r >> 2) + 4 * hi, 64);
  #pragma unroll
  for (int db = 0; db < 2; ++db)
    #pragma unroll
    for (int r = 0; r < 16; ++r) {
      const int qr = (r & 3) + 8 * (r >> 2) + 4 * hi;
      optr[(size_t)(qw + qr) * DH + db * 32 + l31] = oacc[db][r] * iw[r];
    }
}

extern "C" void kernel_launch(void* const* d_in, const int* in_sizes, int n_in,
                              void* d_out, int out_size, void* d_ws, size_t ws_size,
                              hipStream_t stream) {
  const float* q  = (const float*)d_in[0];
  const float* v  = (const float*)d_in[1];
  const float* k  = (const float*)d_in[2];
  const float* am = (const float*)d_in[3];
  const float* sm = (const float*)d_in[4];
  float* o = (float*)d_out;

  dim3 grid(32, S_LEN / QBLK);  // (b*h, q-tile of 32) = 2048 one-wave blocks
  attn_fwd<<<grid, 64, 0, stream>>>(q, v, k, am, sm, o);
}